// Round 2
// baseline (158.275 us; speedup 1.0000x reference)
//
#include <hip/hip_runtime.h>
#include <hip/hip_bf16.h>

#define N_NODES 50000
#define N_EDGES 800000
#define FDIM 64
#define NBUCK 196          // ceil(50000/256) buckets of 256 nodes
#define CAP 4608           // per-bucket ebuf capacity: mean 4096 + 8 sigma (CAP/256 = 18 exactly)
#define CAP2 5632          // per-bucket csr capacity (8-aligned rows: mean ~4996 + 9 sigma)
#define PAD 16             // one counter per 64B line

typedef __attribute__((ext_vector_type(8))) short short8;
typedef __attribute__((ext_vector_type(4))) float f32x4;

// fp32 -> bf16 bits, round-to-nearest-even
__device__ __forceinline__ unsigned f2bf(float f) {
    unsigned u = __float_as_uint(f);
    u += 0x7fffu + ((u >> 16) & 1u);
    return u >> 16;
}
__device__ __forceinline__ float bf2f_lo(unsigned u) { return __uint_as_float(u << 16); }
__device__ __forceinline__ float bf2f_hi(unsigned u) { return __uint_as_float(u & 0xffff0000u); }

// exclusive scan of one value per thread across a 256-thread block
__device__ __forceinline__ int excl_scan_256(int v, int* wtot, int* wincl) {
    const int t = threadIdx.x, lane = t & 63, w = t >> 6;
    int sv = v;
#pragma unroll
    for (int off = 1; off < 64; off <<= 1) {
        int u = __shfl_up(sv, off, 64);
        if (lane >= off) sv += u;
    }
    if (lane == 63) wtot[w] = sv;
    __syncthreads();
    if (w == 0 && lane < 4) {
        int incl = 0;
#pragma unroll
        for (int k = 0; k < 4; ++k)
            if (k <= lane) incl += wtot[k];
        wincl[lane] = incl;
    }
    __syncthreads();
    return (w ? wincl[w - 1] : 0) + sv - v;
}

// ---------------------------------------------------------------------------
// mega-preprocess (fused, all block-families independent):
//   [0,3124]    convert x0 -> bf16
//   [3125,3128] pack weights into MFMA B-fragment order
//   [3129,3910] bucket scatter into fixed regions [bk*CAP,...) of ebuf
//               (edges loaded as int4 quads: E%4==0 so quads never straddle)
// ---------------------------------------------------------------------------
__global__ __launch_bounds__(256)
void preprocess_kernel(const float* __restrict__ x0, unsigned short* __restrict__ x_bf,
                       const float* __restrict__ Wl0, const float* __restrict__ Wr0,
                       const float* __restrict__ Wl1, const float* __restrict__ Wr1,
                       unsigned short* __restrict__ pW,
                       const int* __restrict__ src, const int* __restrict__ dst,
                       int* __restrict__ cur_pad, unsigned* __restrict__ ebuf) {
    const int b = blockIdx.x;
    const int t = threadIdx.x;
    if (b < 3125) {                       // convert: 3125*256*4 = 3.2M exactly
        int i = (b * 256 + t) * 4;
        float4 v = *(const float4*)(x0 + i);
        uint2 o;
        o.x = f2bf(v.x) | (f2bf(v.y) << 16);
        o.y = f2bf(v.z) | (f2bf(v.w) << 16);
        *(uint2*)(x_bf + i) = o;
    } else if (b < 3129) {                // pack W into MFMA B-fragment order
        const float* Wsrc[4] = {Wl0, Wr0, Wl1, Wr1};
        const float* W = Wsrc[b - 3125];
        unsigned short* P = pW + (b - 3125) * FDIM * FDIM;
        for (int idx = t; idx < FDIM * FDIM; idx += 256) {
            int j = idx & 7;
            int lane = (idx >> 3) & 63;
            int g = idx >> 9;             // ct*2 + kk
            int ct = g >> 1, kk = g & 1;
            int k = kk * 32 + ((lane >> 4) & 3) * 8 + j;
            int col = ct * 16 + (lane & 15);
            P[idx] = (unsigned short)f2bf(W[k * FDIM + col]);
        }
    } else {                              // bucket scatter: 782 blocks x 1024 edges
        __shared__ int h[NBUCK];
        __shared__ int base[NBUCK];
        if (t < NBUCK) h[t] = 0;
        __syncthreads();

        int e0 = (b - 3129) * 1024 + t * 4;
        int bk0 = -1, bk1 = -1, bk2 = -1, bk3 = -1;
        int rk0 = 0, rk1 = 0, rk2 = 0, rk3 = 0;
        unsigned pk0 = 0, pk1 = 0, pk2 = 0, pk3 = 0;
        const bool ok = (e0 < N_EDGES);   // quads are fully in-range or fully out
        if (ok) {
            int4 s4 = *(const int4*)(src + e0);
            int4 d4 = *(const int4*)(dst + e0);
            bk0 = d4.x >> 8; pk0 = ((unsigned)d4.x << 16) | (unsigned)s4.x;
            bk1 = d4.y >> 8; pk1 = ((unsigned)d4.y << 16) | (unsigned)s4.y;
            bk2 = d4.z >> 8; pk2 = ((unsigned)d4.z << 16) | (unsigned)s4.z;
            bk3 = d4.w >> 8; pk3 = ((unsigned)d4.w << 16) | (unsigned)s4.w;
            rk0 = atomicAdd(&h[bk0], 1);
            rk1 = atomicAdd(&h[bk1], 1);
            rk2 = atomicAdd(&h[bk2], 1);
            rk3 = atomicAdd(&h[bk3], 1);
        }
        __syncthreads();
        if (t < NBUCK) {
            int c = h[t];
            base[t] = c ? (t * CAP + atomicAdd(&cur_pad[t * PAD], c)) : 0;
        }
        __syncthreads();
        if (ok) {
            ebuf[base[bk0] + rk0] = pk0;
            ebuf[base[bk1] + rk1] = pk1;
            ebuf[base[bk2] + rk2] = pk2;
            ebuf[base[bk3] + rk3] = pk3;
        }
    }
}

// ---------------------------------------------------------------------------
// bucket CSR finalize: one block per bucket (256 nodes).
// Single global pass into registers (CAP/256 = 18, static unroll), LDS
// histogram, 8-aligned exclusive scan -> row_start/deg, LDS csr image,
// coalesced uint4 writeback.
// NEW: also accumulates a global 64-bin degree histogram (LDS-reduced) used
// by perm_kernel's counting sort.
// ---------------------------------------------------------------------------
__global__ __launch_bounds__(256)
void bucket_csr_kernel(const unsigned* __restrict__ ebuf, const int* __restrict__ cur_pad,
                       int* __restrict__ row_start, unsigned short* __restrict__ degs,
                       unsigned short* __restrict__ csr, int* __restrict__ ghist) {
    __shared__ int cnt[256];
    __shared__ int cur[256];
    __shared__ int lh[64];
    __shared__ int wtot[4], wincl[4];
    __shared__ __align__(16) unsigned short sC[CAP2];
    const int b = blockIdx.x;
    const int t = threadIdx.x;
    const int s = b * CAP;                // ebuf window
    const int m = cur_pad[b * PAD];       // edges in this bucket (<= CAP)
    const int s2 = b * CAP2;              // csr window (8-aligned rows)

    cnt[t] = 0;
    if (t < 64) lh[t] = 0;
    __syncthreads();

    // one global pass: load to registers + LDS histogram (18 loads in flight)
    unsigned pk[18];
#pragma unroll
    for (int k = 0; k < 18; ++k) {
        int i = k * 256 + t;
        if (i < m) {
            pk[k] = ebuf[s + i];
            atomicAdd(&cnt[(pk[k] >> 16) & 255], 1);
        }
    }
    __syncthreads();

    int c = cnt[t];
    int node = b * 256 + t;
    if (node < N_NODES) atomicAdd(&lh[c > 63 ? 63 : c], 1);   // degree-bin hist
    int c8 = (c + 7) & ~7;                // 8-aligned segment size
    int ex = excl_scan_256(c8, wtot, wincl);   // contains syncthreads -> lh done after
    cur[t] = ex;                          // LOCAL (bucket-relative) cursor
    if (node < N_NODES) {
        row_start[node] = s2 + ex;
        degs[node] = (unsigned short)c;
    }
    __syncthreads();

    if (t < 64) {                         // flush degree histogram (lh final: scan synced)
        int v = lh[t];
        if (v) atomicAdd(&ghist[t], v);
    }

    // scatter into LDS csr image
#pragma unroll
    for (int k = 0; k < 18; ++k) {
        int i = k * 256 + t;
        if (i < m) {
            int pos = atomicAdd(&cur[(pk[k] >> 16) & 255], 1);
            sC[pos] = (unsigned short)pk[k];
        }
    }
    __syncthreads();

    // coalesced writeback of the used prefix (tot is a multiple of 8)
    const int tot = wincl[3];
    for (int i = t * 8; i < tot; i += 2048)
        *(uint4*)(csr + s2 + i) = *(const uint4*)(&sC[i]);
}

// ---------------------------------------------------------------------------
// counting-sort permutation by degree (64 clamped bins). perm[pos] lists node
// ids in non-decreasing-degree order, so consecutive nodes -> equal degrees ->
// the sage gather loop has no per-slot trip-count divergence. Order within a
// bin is arbitrary (atomics) -- irrelevant for balancing and for correctness.
// ---------------------------------------------------------------------------
__global__ __launch_bounds__(256)
void perm_kernel(const unsigned short* __restrict__ degs,
                 const int* __restrict__ ghist, int* __restrict__ gcur,
                 int* __restrict__ perm) {
    __shared__ int lg[64];     // global hist copy
    __shared__ int lh[64];     // this block's hist
    __shared__ int lcur[64];   // absolute write cursor per bin
    const int b = blockIdx.x, t = threadIdx.x;
    if (t < 64) { lg[t] = ghist[t]; lh[t] = 0; }
    __syncthreads();
    const int node = b * 256 + t;
    int bin = 0;
    if (node < N_NODES) {
        bin = degs[node]; if (bin > 63) bin = 63;
        atomicAdd(&lh[bin], 1);
    }
    __syncthreads();
    if (t < 64) {
        int ex = 0;                       // exclusive scan of global hist
        for (int k = 0; k < t; ++k) ex += lg[k];
        int cc = lh[t];
        lcur[t] = ex + (cc ? atomicAdd(&gcur[t], cc) : 0);   // reserve block range
    }
    __syncthreads();
    if (node < N_NODES) {
        int pos = atomicAdd(&lcur[bin], 1);
        perm[pos] = node;
    }
}

// ---------------------------------------------------------------------------
// fused SAGE layer, slot-parallel gather with batched index loads.
// Block = 128 (2 waves), 16 nodes. Wave = 8 slots x 8 lanes; slot owns node
// n = perm[base + r] (degree-sorted -> all 16 nodes of a block have ~equal
// degree -> no exec-mask divergence in the batch loop, block sync is tight).
// Indices come 8-at-a-time via one 16B-aligned uint4 load; 8 row loads in
// flight per slot; next index batch prefetched across the back-edge.
// mean+self staged in LDS bf16, octs XOR-swizzled by row&7. MFMA: wave w does
// col-tiles 2w,2w+1.
// A[m=lane&15][k=(lane>>4)*8+j]; C/D: col=lane&15, row=(lane>>4)*4+reg.
// Grid 3125 (x16 = 50000 exactly).
// ---------------------------------------------------------------------------
template <bool OUT_BF16>
__global__ __launch_bounds__(128)
void sage_fused_kernel(const unsigned short* __restrict__ xb,
                       const int* __restrict__ row_start,
                       const unsigned short* __restrict__ degs,
                       const unsigned short* __restrict__ csr,
                       const int* __restrict__ perm,
                       const unsigned short* __restrict__ pWl,
                       const float* __restrict__ bl,
                       const unsigned short* __restrict__ pWr,
                       float* __restrict__ out_f32,
                       unsigned short* __restrict__ out_bf) {
    __shared__ __align__(16) unsigned short smean[16][FDIM];
    __shared__ __align__(16) unsigned short sxs[16][FDIM];

    const int w = threadIdx.x >> 6;       // 0..1
    const int lane = threadIdx.x & 63;
    const int slot = lane >> 3;           // 0..7 -> node within wave
    const int c = lane & 7;               // col-oct 0..7
    const int base = blockIdx.x * 16;
    const int r = w * 8 + slot;           // local row 0..15
    const int n = perm[base + r];         // degree-sorted node id

    // self row first (issues earliest)
    uint4 sv = *(const uint4*)(xb + (size_t)n * FDIM + c * 8);

    const int rs = row_start[n];
    const int deg = degs[n];
    const int po = (c ^ (r & 7)) * 8;     // swizzled physical oct offset

    *(uint4*)(&sxs[r][po]) = sv;
    float s0 = bf2f_lo(sv.x), s1 = bf2f_hi(sv.x);
    float s2 = bf2f_lo(sv.y), s3 = bf2f_hi(sv.y);
    float s4 = bf2f_lo(sv.z), s5 = bf2f_hi(sv.z);
    float s6 = bf2f_lo(sv.w), s7 = bf2f_hi(sv.w);

#define ACC(v_) do {                                   \
        s0 += bf2f_lo(v_.x); s1 += bf2f_hi(v_.x);      \
        s2 += bf2f_lo(v_.y); s3 += bf2f_hi(v_.y);      \
        s4 += bf2f_lo(v_.z); s5 += bf2f_hi(v_.z);      \
        s6 += bf2f_lo(v_.w); s7 += bf2f_hi(v_.w);      \
    } while (0)

    int idx = rs;                         // 8-aligned by construction
    int rem = deg;
    uint4 iA = *(const uint4*)(csr + idx);   // first index batch (unused if deg==0)
    while (rem >= 8) {
        int a0 = iA.x & 0xffff, a1 = iA.x >> 16;
        int a2 = iA.y & 0xffff, a3 = iA.y >> 16;
        int a4 = iA.z & 0xffff, a5 = iA.z >> 16;
        int a6 = iA.w & 0xffff, a7 = iA.w >> 16;
        uint4 v0 = *(const uint4*)(xb + (size_t)a0 * FDIM + c * 8);
        uint4 v1 = *(const uint4*)(xb + (size_t)a1 * FDIM + c * 8);
        uint4 v2 = *(const uint4*)(xb + (size_t)a2 * FDIM + c * 8);
        uint4 v3 = *(const uint4*)(xb + (size_t)a3 * FDIM + c * 8);
        uint4 v4 = *(const uint4*)(xb + (size_t)a4 * FDIM + c * 8);
        uint4 v5 = *(const uint4*)(xb + (size_t)a5 * FDIM + c * 8);
        uint4 v6 = *(const uint4*)(xb + (size_t)a6 * FDIM + c * 8);
        uint4 v7 = *(const uint4*)(xb + (size_t)a7 * FDIM + c * 8);
        if (rem > 8)                      // prefetch next index batch across back-edge
            iA = *(const uint4*)(csr + idx + 8);
        ACC(v0); ACC(v1); ACC(v2); ACC(v3);
        ACC(v4); ACC(v5); ACC(v6); ACC(v7);
        idx += 8; rem -= 8;
    }
    if (rem > 0) {                        // tail: iA already holds csr[idx]
        int a[8];
        a[0] = iA.x & 0xffff; a[1] = iA.x >> 16;
        a[2] = iA.y & 0xffff; a[3] = iA.y >> 16;
        a[4] = iA.z & 0xffff; a[5] = iA.z >> 16;
        a[6] = iA.w & 0xffff; a[7] = iA.w >> 16;
#pragma unroll
        for (int k = 0; k < 8; ++k) {
            if (k < rem) {
                uint4 v = *(const uint4*)(xb + (size_t)a[k] * FDIM + c * 8);
                ACC(v);
            }
        }
    }
#undef ACC

    const float inv = 1.0f / (float)(deg + 1);
    uint4 o;
    o.x = f2bf(s0 * inv) | (f2bf(s1 * inv) << 16);
    o.y = f2bf(s2 * inv) | (f2bf(s3 * inv) << 16);
    o.z = f2bf(s4 * inv) | (f2bf(s5 * inv) << 16);
    o.w = f2bf(s6 * inv) | (f2bf(s7 * inv) << 16);
    *(uint4*)(&smean[r][po]) = o;
    __syncthreads();

    // ---- MFMA phase: wave w -> col-tiles 2w, 2w+1 ----
    const int qq = lane >> 4;
    const int rr = lane & 15;

    short8 am0 = *(const short8*)(&smean[rr][((0 + qq) ^ (rr & 7)) * 8]);
    short8 am1 = *(const short8*)(&smean[rr][((4 + qq) ^ (rr & 7)) * 8]);
    short8 ax0 = *(const short8*)(&sxs[rr][((0 + qq) ^ (rr & 7)) * 8]);
    short8 ax1 = *(const short8*)(&sxs[rr][((4 + qq) ^ (rr & 7)) * 8]);

    // output rows for this thread's 4 accumulator regs (perm hot in L1)
    int nd[4];
#pragma unroll
    for (int reg = 0; reg < 4; ++reg) nd[reg] = perm[base + qq * 4 + reg];

    const short8* pl = (const short8*)pWl;
    const short8* pr = (const short8*)pWr;

#pragma unroll
    for (int tk = 0; tk < 2; ++tk) {
        const int ct = w * 2 + tk;
        short8 bl0v = pl[(ct * 2 + 0) * 64 + lane];
        short8 bl1v = pl[(ct * 2 + 1) * 64 + lane];
        short8 br0v = pr[(ct * 2 + 0) * 64 + lane];
        short8 br1v = pr[(ct * 2 + 1) * 64 + lane];

        float b = bl[ct * 16 + rr];
        f32x4 acc = {b, b, b, b};
        acc = __builtin_amdgcn_mfma_f32_16x16x32_bf16(am0, bl0v, acc, 0, 0, 0);
        acc = __builtin_amdgcn_mfma_f32_16x16x32_bf16(am1, bl1v, acc, 0, 0, 0);
        acc = __builtin_amdgcn_mfma_f32_16x16x32_bf16(ax0, br0v, acc, 0, 0, 0);
        acc = __builtin_amdgcn_mfma_f32_16x16x32_bf16(ax1, br1v, acc, 0, 0, 0);

#pragma unroll
        for (int reg = 0; reg < 4; ++reg) {
            float v = fmaxf(acc[reg], 0.0f);
            if (OUT_BF16) out_bf[(size_t)nd[reg] * FDIM + ct * 16 + rr] = (unsigned short)f2bf(v);
            else          out_f32[(size_t)nd[reg] * FDIM + ct * 16 + rr] = v;
        }
    }
}

// ---------------------------------------------------------------------------
extern "C" void kernel_launch(void* const* d_in, const int* in_sizes, int n_in,
                              void* d_out, int out_size, void* d_ws, size_t ws_size,
                              hipStream_t stream) {
    const float* x0  = (const float*)d_in[0];
    const int*   ei  = (const int*)d_in[1];
    const float* Wl0 = (const float*)d_in[2];
    const float* bl0 = (const float*)d_in[3];
    const float* Wr0 = (const float*)d_in[4];
    const float* Wl1 = (const float*)d_in[5];
    const float* bl1 = (const float*)d_in[6];
    const float* Wr1 = (const float*)d_in[7];
    float* out = (float*)d_out;

    const int* src = ei;            // edge_index[0]
    const int* dst = ei + N_EDGES;  // edge_index[1]

    // workspace layout (all segments 16B-aligned by construction):
    // cur_pad[3136] ghist[64] gcur[64] | row_start[50000] | perm[50000] |
    // degs u16[50000] | ebuf[196*4608] | csr u16[196*5632 + 1024 slack] |
    // x_bf | h_bf | pW(4x4096)
    int* cur_pad    = (int*)d_ws;                        // 3136 ints
    int* ghist      = cur_pad + 3136;                    // 64 ints
    int* gcur       = cur_pad + 3200;                    // 64 ints
    int* row_start  = cur_pad + 3264;                    // 50000 ints
    int* perm       = row_start + 50000;                 // 50000 ints
    unsigned short* degs = (unsigned short*)(perm + 50000);        // 50000
    unsigned* ebuf  = (unsigned*)(degs + 50000);         // 903168 uints
    unsigned short* csr_u16 = (unsigned short*)(ebuf + NBUCK * CAP);
    unsigned short* x_bf = csr_u16 + (NBUCK * CAP2 + 1024);
    unsigned short* h_bf = x_bf + (size_t)N_NODES * FDIM;
    unsigned short* pW   = h_bf + (size_t)N_NODES * FDIM;   // 4 x 4096

    hipMemsetAsync(cur_pad, 0, 3264 * sizeof(int), stream);   // cur_pad + ghist + gcur
    preprocess_kernel<<<3911, 256, 0, stream>>>(x0, x_bf, Wl0, Wr0, Wl1, Wr1,
                                                pW, src, dst, cur_pad, ebuf);
    bucket_csr_kernel<<<NBUCK, 256, 0, stream>>>(ebuf, cur_pad, row_start, degs,
                                                 csr_u16, ghist);
    perm_kernel<<<NBUCK, 256, 0, stream>>>(degs, ghist, gcur, perm);

    // ---- layer 0 (bf16 out) ----
    sage_fused_kernel<true><<<N_NODES / 16, 128, 0, stream>>>(
        x_bf, row_start, degs, csr_u16, perm, pW + 0 * FDIM * FDIM, bl0,
        pW + 1 * FDIM * FDIM, nullptr, h_bf);
    // ---- layer 1 (fp32 out) ----
    sage_fused_kernel<false><<<N_NODES / 16, 128, 0, stream>>>(
        h_bf, row_start, degs, csr_u16, perm, pW + 2 * FDIM * FDIM, bl1,
        pW + 3 * FDIM * FDIM, out, nullptr);
}

// Round 4
// 147.874 us; speedup vs baseline: 1.0703x; 1.0703x over previous
//
#include <hip/hip_runtime.h>
#include <hip/hip_bf16.h>

#define N_NODES 50000
#define N_EDGES 800000
#define FDIM 64
#define NBUCK 196          // ceil(50000/256) buckets of 256 nodes
#define CAP 4608           // per-bucket ebuf capacity: mean 4096 + 8 sigma (CAP/256 = 18 exactly)
#define CAP2 5632          // per-bucket csr capacity (8-aligned rows: mean ~4996 + 9 sigma)
#define PAD 16             // one counter per 64B line
#define ZROW 50000         // index of the all-zero pad row in x_bf / h_bf

typedef __attribute__((ext_vector_type(8))) short short8;
typedef __attribute__((ext_vector_type(4))) float f32x4;

// fp32 -> bf16 bits, round-to-nearest-even
__device__ __forceinline__ unsigned f2bf(float f) {
    unsigned u = __float_as_uint(f);
    u += 0x7fffu + ((u >> 16) & 1u);
    return u >> 16;
}
__device__ __forceinline__ float bf2f_lo(unsigned u) { return __uint_as_float(u << 16); }
__device__ __forceinline__ float bf2f_hi(unsigned u) { return __uint_as_float(u & 0xffff0000u); }

// exclusive scan of one value per thread across a 256-thread block
__device__ __forceinline__ int excl_scan_256(int v, int* wtot, int* wincl) {
    const int t = threadIdx.x, lane = t & 63, w = t >> 6;
    int sv = v;
#pragma unroll
    for (int off = 1; off < 64; off <<= 1) {
        int u = __shfl_up(sv, off, 64);
        if (lane >= off) sv += u;
    }
    if (lane == 63) wtot[w] = sv;
    __syncthreads();
    if (w == 0 && lane < 4) {
        int incl = 0;
#pragma unroll
        for (int k = 0; k < 4; ++k)
            if (k <= lane) incl += wtot[k];
        wincl[lane] = incl;
    }
    __syncthreads();
    return (w ? wincl[w - 1] : 0) + sv - v;
}

// ---------------------------------------------------------------------------
// mega-preprocess (fused, all block-families independent):
//   [0,3124]    convert x0 -> bf16
//   [3125]      zero the pad row (ZROW) of x_bf and h_bf
//   [3126,3129] pack weights into MFMA B-fragment order
//   [3130,3911] bucket scatter into fixed regions [bk*CAP,...) of ebuf
//               (edges loaded as int4 quads: E%4==0 so quads never straddle)
// ---------------------------------------------------------------------------
__global__ __launch_bounds__(256)
void preprocess_kernel(const float* __restrict__ x0, unsigned short* __restrict__ x_bf,
                       unsigned short* __restrict__ h_bf,
                       const float* __restrict__ Wl0, const float* __restrict__ Wr0,
                       const float* __restrict__ Wl1, const float* __restrict__ Wr1,
                       unsigned short* __restrict__ pW,
                       const int* __restrict__ src, const int* __restrict__ dst,
                       int* __restrict__ cur_pad, unsigned* __restrict__ ebuf) {
    const int b = blockIdx.x;
    const int t = threadIdx.x;
    if (b < 3125) {                       // convert: 3125*256*4 = 3.2M exactly
        int i = (b * 256 + t) * 4;
        float4 v = *(const float4*)(x0 + i);
        uint2 o;
        o.x = f2bf(v.x) | (f2bf(v.y) << 16);
        o.y = f2bf(v.z) | (f2bf(v.w) << 16);
        *(uint2*)(x_bf + i) = o;
    } else if (b == 3125) {               // zero pad rows (gather target for csr pads)
        uint4 z = {0, 0, 0, 0};
        if (t < 8)       *(uint4*)(x_bf + (size_t)ZROW * FDIM + t * 8) = z;
        else if (t < 16) *(uint4*)(h_bf + (size_t)ZROW * FDIM + (t - 8) * 8) = z;
    } else if (b < 3130) {                // pack W into MFMA B-fragment order
        const float* Wsrc[4] = {Wl0, Wr0, Wl1, Wr1};
        const float* W = Wsrc[b - 3126];
        unsigned short* P = pW + (b - 3126) * FDIM * FDIM;
        for (int idx = t; idx < FDIM * FDIM; idx += 256) {
            int j = idx & 7;
            int lane = (idx >> 3) & 63;
            int g = idx >> 9;             // ct*2 + kk
            int ct = g >> 1, kk = g & 1;
            int k = kk * 32 + ((lane >> 4) & 3) * 8 + j;
            int col = ct * 16 + (lane & 15);
            P[idx] = (unsigned short)f2bf(W[k * FDIM + col]);
        }
    } else {                              // bucket scatter: 782 blocks x 1024 edges
        __shared__ int h[NBUCK];
        __shared__ int base[NBUCK];
        if (t < NBUCK) h[t] = 0;
        __syncthreads();

        int e0 = (b - 3130) * 1024 + t * 4;
        int bk0 = -1, bk1 = -1, bk2 = -1, bk3 = -1;
        int rk0 = 0, rk1 = 0, rk2 = 0, rk3 = 0;
        unsigned pk0 = 0, pk1 = 0, pk2 = 0, pk3 = 0;
        const bool ok = (e0 < N_EDGES);   // quads are fully in-range or fully out
        if (ok) {
            int4 s4 = *(const int4*)(src + e0);
            int4 d4 = *(const int4*)(dst + e0);
            bk0 = d4.x >> 8; pk0 = ((unsigned)d4.x << 16) | (unsigned)s4.x;
            bk1 = d4.y >> 8; pk1 = ((unsigned)d4.y << 16) | (unsigned)s4.y;
            bk2 = d4.z >> 8; pk2 = ((unsigned)d4.z << 16) | (unsigned)s4.z;
            bk3 = d4.w >> 8; pk3 = ((unsigned)d4.w << 16) | (unsigned)s4.w;
            rk0 = atomicAdd(&h[bk0], 1);
            rk1 = atomicAdd(&h[bk1], 1);
            rk2 = atomicAdd(&h[bk2], 1);
            rk3 = atomicAdd(&h[bk3], 1);
        }
        __syncthreads();
        if (t < NBUCK) {
            int c = h[t];
            base[t] = c ? (t * CAP + atomicAdd(&cur_pad[t * PAD], c)) : 0;
        }
        __syncthreads();
        if (ok) {
            ebuf[base[bk0] + rk0] = pk0;
            ebuf[base[bk1] + rk1] = pk1;
            ebuf[base[bk2] + rk2] = pk2;
            ebuf[base[bk3] + rk3] = pk3;
        }
    }
}

// ---------------------------------------------------------------------------
// bucket CSR finalize: one block per bucket (256 nodes).
// Single global pass into registers (CAP/256 = 18, static unroll), LDS
// histogram, 8-aligned exclusive scan -> row_start/deg, LDS csr image,
// pad-fill each node's segment tail [deg, ceil8(deg)) with ZROW (gathers of
// pads read the zero row -> sage loop needs no tail), coalesced uint4
// writeback.
// ---------------------------------------------------------------------------
__global__ __launch_bounds__(256)
void bucket_csr_kernel(const unsigned* __restrict__ ebuf, const int* __restrict__ cur_pad,
                       int* __restrict__ row_start, unsigned short* __restrict__ degs,
                       unsigned short* __restrict__ csr) {
    __shared__ int cnt[256];
    __shared__ int cur[256];
    __shared__ int wtot[4], wincl[4];
    __shared__ __align__(16) unsigned short sC[CAP2];
    const int b = blockIdx.x;
    const int t = threadIdx.x;
    const int s = b * CAP;                // ebuf window
    const int m = cur_pad[b * PAD];       // edges in this bucket (<= CAP)
    const int s2 = b * CAP2;              // csr window (8-aligned rows)

    cnt[t] = 0;
    __syncthreads();

    // one global pass: load to registers + LDS histogram (18 loads in flight)
    unsigned pk[18];
#pragma unroll
    for (int k = 0; k < 18; ++k) {
        int i = k * 256 + t;
        if (i < m) {
            pk[k] = ebuf[s + i];
            atomicAdd(&cnt[(pk[k] >> 16) & 255], 1);
        }
    }
    __syncthreads();

    int c = cnt[t];
    int c8 = (c + 7) & ~7;                // 8-aligned segment size
    int ex = excl_scan_256(c8, wtot, wincl);
    cur[t] = ex;                          // LOCAL (bucket-relative) cursor
    int node = b * 256 + t;
    if (node < N_NODES) {
        row_start[node] = s2 + ex;
        degs[node] = (unsigned short)c;
    }
    __syncthreads();

    // scatter into LDS csr image
#pragma unroll
    for (int k = 0; k < 18; ++k) {
        int i = k * 256 + t;
        if (i < m) {
            int pos = atomicAdd(&cur[(pk[k] >> 16) & 255], 1);
            sC[pos] = (unsigned short)pk[k];
        }
    }
    __syncthreads();

    // pad each node's segment tail with ZROW (zero-row gather target)
    for (int i = c; i < c8; ++i)
        sC[ex + i] = (unsigned short)ZROW;
    __syncthreads();

    // coalesced writeback of the used prefix (tot is a multiple of 8)
    const int tot = wincl[3];
    for (int i = t * 8; i < tot; i += 2048)
        *(uint4*)(csr + s2 + i) = *(const uint4*)(&sC[i]);
}

// ---------------------------------------------------------------------------
// fused SAGE layer, slot-parallel gather with batched index loads.
// Block = 128 (2 waves), 16 nodes. Wave = 8 slots x 8 lanes; slot owns node
// r = w*8+slot; lane covers col-oct c. Indices come 8-at-a-time via one
// 16B-aligned uint4 load; 8 row loads in flight per slot; next index batch
// prefetched across the back-edge. Segments are padded to a multiple of 8
// with ZROW (zero row) -> NO tail code at all; mean divides by true deg+1.
// mean+self staged in LDS bf16, octs XOR-swizzled by row&7. MFMA: wave w does
// col-tiles 2w,2w+1.
// A[m=lane&15][k=(lane>>4)*8+j]; C/D: col=lane&15, row=(lane>>4)*4+reg.
// Grid 3125 (x16 = 50000 exactly).
// ---------------------------------------------------------------------------
template <bool OUT_BF16>
__global__ __launch_bounds__(128)
void sage_fused_kernel(const unsigned short* __restrict__ xb,
                       const int* __restrict__ row_start,
                       const unsigned short* __restrict__ degs,
                       const unsigned short* __restrict__ csr,
                       const unsigned short* __restrict__ pWl,
                       const float* __restrict__ bl,
                       const unsigned short* __restrict__ pWr,
                       float* __restrict__ out_f32,
                       unsigned short* __restrict__ out_bf) {
    __shared__ __align__(16) unsigned short smean[16][FDIM];
    __shared__ __align__(16) unsigned short sxs[16][FDIM];

    const int w = threadIdx.x >> 6;       // 0..1
    const int lane = threadIdx.x & 63;
    const int slot = lane >> 3;           // 0..7 -> node within wave
    const int c = lane & 7;               // col-oct 0..7
    const int base = blockIdx.x * 16;
    const int r = w * 8 + slot;           // local row 0..15
    const int n = base + r;

    // self row first (issues earliest)
    uint4 sv = *(const uint4*)(xb + (size_t)n * FDIM + c * 8);

    const int rs = row_start[n];
    const int deg = degs[n];
    const int po = (c ^ (r & 7)) * 8;     // swizzled physical oct offset

    *(uint4*)(&sxs[r][po]) = sv;
    float s0 = bf2f_lo(sv.x), s1 = bf2f_hi(sv.x);
    float s2 = bf2f_lo(sv.y), s3 = bf2f_hi(sv.y);
    float s4 = bf2f_lo(sv.z), s5 = bf2f_hi(sv.z);
    float s6 = bf2f_lo(sv.w), s7 = bf2f_hi(sv.w);

#define ACC(v_) do {                                   \
        s0 += bf2f_lo(v_.x); s1 += bf2f_hi(v_.x);      \
        s2 += bf2f_lo(v_.y); s3 += bf2f_hi(v_.y);      \
        s4 += bf2f_lo(v_.z); s5 += bf2f_hi(v_.z);      \
        s6 += bf2f_lo(v_.w); s7 += bf2f_hi(v_.w);      \
    } while (0)

    const int nb = (deg + 7) >> 3;        // segments padded to x8 with ZROW
    int idx = rs;                         // 8-aligned by construction
    uint4 iA = *(const uint4*)(csr + idx);   // first index batch (unused if nb==0)
    for (int it = 0; it < nb; ++it) {
        int a0 = iA.x & 0xffff, a1 = iA.x >> 16;
        int a2 = iA.y & 0xffff, a3 = iA.y >> 16;
        int a4 = iA.z & 0xffff, a5 = iA.z >> 16;
        int a6 = iA.w & 0xffff, a7 = iA.w >> 16;
        uint4 v0 = *(const uint4*)(xb + (size_t)a0 * FDIM + c * 8);
        uint4 v1 = *(const uint4*)(xb + (size_t)a1 * FDIM + c * 8);
        uint4 v2 = *(const uint4*)(xb + (size_t)a2 * FDIM + c * 8);
        uint4 v3 = *(const uint4*)(xb + (size_t)a3 * FDIM + c * 8);
        uint4 v4 = *(const uint4*)(xb + (size_t)a4 * FDIM + c * 8);
        uint4 v5 = *(const uint4*)(xb + (size_t)a5 * FDIM + c * 8);
        uint4 v6 = *(const uint4*)(xb + (size_t)a6 * FDIM + c * 8);
        uint4 v7 = *(const uint4*)(xb + (size_t)a7 * FDIM + c * 8);
        if (it + 1 < nb)                  // prefetch next index batch across back-edge
            iA = *(const uint4*)(csr + idx + 8);
        ACC(v0); ACC(v1); ACC(v2); ACC(v3);
        ACC(v4); ACC(v5); ACC(v6); ACC(v7);
        idx += 8;
    }
#undef ACC

    const float inv = 1.0f / (float)(deg + 1);
    uint4 o;
    o.x = f2bf(s0 * inv) | (f2bf(s1 * inv) << 16);
    o.y = f2bf(s2 * inv) | (f2bf(s3 * inv) << 16);
    o.z = f2bf(s4 * inv) | (f2bf(s5 * inv) << 16);
    o.w = f2bf(s6 * inv) | (f2bf(s7 * inv) << 16);
    *(uint4*)(&smean[r][po]) = o;
    __syncthreads();

    // ---- MFMA phase: wave w -> col-tiles 2w, 2w+1 ----
    const int qq = lane >> 4;
    const int rr = lane & 15;

    short8 am0 = *(const short8*)(&smean[rr][((0 + qq) ^ (rr & 7)) * 8]);
    short8 am1 = *(const short8*)(&smean[rr][((4 + qq) ^ (rr & 7)) * 8]);
    short8 ax0 = *(const short8*)(&sxs[rr][((0 + qq) ^ (rr & 7)) * 8]);
    short8 ax1 = *(const short8*)(&sxs[rr][((4 + qq) ^ (rr & 7)) * 8]);

    const short8* pl = (const short8*)pWl;
    const short8* pr = (const short8*)pWr;

#pragma unroll
    for (int tk = 0; tk < 2; ++tk) {
        const int ct = w * 2 + tk;
        short8 bl0v = pl[(ct * 2 + 0) * 64 + lane];
        short8 bl1v = pl[(ct * 2 + 1) * 64 + lane];
        short8 br0v = pr[(ct * 2 + 0) * 64 + lane];
        short8 br1v = pr[(ct * 2 + 1) * 64 + lane];

        float b = bl[ct * 16 + rr];
        f32x4 acc = {b, b, b, b};
        acc = __builtin_amdgcn_mfma_f32_16x16x32_bf16(am0, bl0v, acc, 0, 0, 0);
        acc = __builtin_amdgcn_mfma_f32_16x16x32_bf16(am1, bl1v, acc, 0, 0, 0);
        acc = __builtin_amdgcn_mfma_f32_16x16x32_bf16(ax0, br0v, acc, 0, 0, 0);
        acc = __builtin_amdgcn_mfma_f32_16x16x32_bf16(ax1, br1v, acc, 0, 0, 0);

#pragma unroll
        for (int reg = 0; reg < 4; ++reg) {
            int node = base + qq * 4 + reg;
            float v = fmaxf(acc[reg], 0.0f);
            if (OUT_BF16) out_bf[(size_t)node * FDIM + ct * 16 + rr] = (unsigned short)f2bf(v);
            else          out_f32[(size_t)node * FDIM + ct * 16 + rr] = v;
        }
    }
}

// ---------------------------------------------------------------------------
extern "C" void kernel_launch(void* const* d_in, const int* in_sizes, int n_in,
                              void* d_out, int out_size, void* d_ws, size_t ws_size,
                              hipStream_t stream) {
    const float* x0  = (const float*)d_in[0];
    const int*   ei  = (const int*)d_in[1];
    const float* Wl0 = (const float*)d_in[2];
    const float* bl0 = (const float*)d_in[3];
    const float* Wr0 = (const float*)d_in[4];
    const float* Wl1 = (const float*)d_in[5];
    const float* bl1 = (const float*)d_in[6];
    const float* Wr1 = (const float*)d_in[7];
    float* out = (float*)d_out;

    const int* src = ei;            // edge_index[0]
    const int* dst = ei + N_EDGES;  // edge_index[1]

    // workspace layout (all segments 16B-aligned by construction):
    // cur_pad[3136] | row_start[50000] | degs u16[50000] | ebuf[196*4608] |
    // csr u16[196*5632 + 1024 slack] | x_bf[(N+1)*64] | h_bf[(N+1)*64] | pW(4x4096)
    int* cur_pad    = (int*)d_ws;                        // 3136 ints
    int* row_start  = cur_pad + 3136;                    // 50000 ints
    unsigned short* degs = (unsigned short*)(row_start + 50000);   // 50000
    unsigned* ebuf  = (unsigned*)(degs + 50000);         // 903168 uints
    unsigned short* csr_u16 = (unsigned short*)(ebuf + NBUCK * CAP);
    unsigned short* x_bf = csr_u16 + (NBUCK * CAP2 + 1024);
    unsigned short* h_bf = x_bf + (size_t)(N_NODES + 1) * FDIM;
    unsigned short* pW   = h_bf + (size_t)(N_NODES + 1) * FDIM;   // 4 x 4096

    hipMemsetAsync(cur_pad, 0, 3136 * sizeof(int), stream);
    preprocess_kernel<<<3912, 256, 0, stream>>>(x0, x_bf, h_bf, Wl0, Wr0, Wl1, Wr1,
                                                pW, src, dst, cur_pad, ebuf);
    bucket_csr_kernel<<<NBUCK, 256, 0, stream>>>(ebuf, cur_pad, row_start, degs, csr_u16);

    // ---- layer 0 (bf16 out) ----
    sage_fused_kernel<true><<<N_NODES / 16, 128, 0, stream>>>(
        x_bf, row_start, degs, csr_u16, pW + 0 * FDIM * FDIM, bl0,
        pW + 1 * FDIM * FDIM, nullptr, h_bf);
    // ---- layer 1 (fp32 out) ----
    sage_fused_kernel<false><<<N_NODES / 16, 128, 0, stream>>>(
        h_bf, row_start, degs, csr_u16, pW + 2 * FDIM * FDIM, bl1,
        pW + 3 * FDIM * FDIM, out, nullptr);
}

// Round 5
// 147.356 us; speedup vs baseline: 1.0741x; 1.0035x over previous
//
#include <hip/hip_runtime.h>
#include <hip/hip_bf16.h>

#define N_NODES 50000
#define N_EDGES 800000
#define FDIM 64
#define NBUCK 196          // ceil(50000/256) buckets of 256 nodes
#define CAP 4608           // per-bucket ebuf capacity: mean 4096 + 8 sigma
#define CAP2 5632          // per-bucket csr capacity (8-aligned rows: mean ~4996 + 9 sigma)
#define PAD 16             // one counter per 64B line
#define ZROW 50000         // index of the all-zero pad row in x_bf / h_bf

typedef __attribute__((ext_vector_type(8))) short short8;
typedef __attribute__((ext_vector_type(4))) float f32x4;
typedef __attribute__((ext_vector_type(2))) float f32x2;

// fp32 -> bf16 bits, round-to-nearest-even
__device__ __forceinline__ unsigned f2bf(float f) {
    unsigned u = __float_as_uint(f);
    u += 0x7fffu + ((u >> 16) & 1u);
    return u >> 16;
}
__device__ __forceinline__ float bf2f_lo(unsigned u) { return __uint_as_float(u << 16); }
__device__ __forceinline__ float bf2f_hi(unsigned u) { return __uint_as_float(u & 0xffff0000u); }

// ---------------------------------------------------------------------------
// mega-preprocess (fused, all block-families independent):
//   [0,3124]    convert x0 -> bf16
//   [3125]      zero the pad row (ZROW) of x_bf and h_bf
//   [3126,3129] pack weights into MFMA B-fragment order
//   [3130,3911] bucket scatter into fixed regions [bk*CAP,...) of ebuf
//               (edges loaded as int4 quads: E%4==0 so quads never straddle)
// ---------------------------------------------------------------------------
__global__ __launch_bounds__(256)
void preprocess_kernel(const float* __restrict__ x0, unsigned short* __restrict__ x_bf,
                       unsigned short* __restrict__ h_bf,
                       const float* __restrict__ Wl0, const float* __restrict__ Wr0,
                       const float* __restrict__ Wl1, const float* __restrict__ Wr1,
                       unsigned short* __restrict__ pW,
                       const int* __restrict__ src, const int* __restrict__ dst,
                       int* __restrict__ cur_pad, unsigned* __restrict__ ebuf) {
    const int b = blockIdx.x;
    const int t = threadIdx.x;
    if (b < 3125) {                       // convert: 3125*256*4 = 3.2M exactly
        int i = (b * 256 + t) * 4;
        float4 v = *(const float4*)(x0 + i);
        uint2 o;
        o.x = f2bf(v.x) | (f2bf(v.y) << 16);
        o.y = f2bf(v.z) | (f2bf(v.w) << 16);
        *(uint2*)(x_bf + i) = o;
    } else if (b == 3125) {               // zero pad rows (gather target for csr pads)
        uint4 z = {0, 0, 0, 0};
        if (t < 8)       *(uint4*)(x_bf + (size_t)ZROW * FDIM + t * 8) = z;
        else if (t < 16) *(uint4*)(h_bf + (size_t)ZROW * FDIM + (t - 8) * 8) = z;
    } else if (b < 3130) {                // pack W into MFMA B-fragment order
        const float* Wsrc[4] = {Wl0, Wr0, Wl1, Wr1};
        const float* W = Wsrc[b - 3126];
        unsigned short* P = pW + (b - 3126) * FDIM * FDIM;
        for (int idx = t; idx < FDIM * FDIM; idx += 256) {
            int j = idx & 7;
            int lane = (idx >> 3) & 63;
            int g = idx >> 9;             // ct*2 + kk
            int ct = g >> 1, kk = g & 1;
            int k = kk * 32 + ((lane >> 4) & 3) * 8 + j;
            int col = ct * 16 + (lane & 15);
            P[idx] = (unsigned short)f2bf(W[k * FDIM + col]);
        }
    } else {                              // bucket scatter: 782 blocks x 1024 edges
        __shared__ int h[NBUCK];
        __shared__ int base[NBUCK];
        if (t < NBUCK) h[t] = 0;
        __syncthreads();

        int e0 = (b - 3130) * 1024 + t * 4;
        int bk0 = -1, bk1 = -1, bk2 = -1, bk3 = -1;
        int rk0 = 0, rk1 = 0, rk2 = 0, rk3 = 0;
        unsigned pk0 = 0, pk1 = 0, pk2 = 0, pk3 = 0;
        const bool ok = (e0 < N_EDGES);   // quads are fully in-range or fully out
        if (ok) {
            int4 s4 = *(const int4*)(src + e0);
            int4 d4 = *(const int4*)(dst + e0);
            bk0 = d4.x >> 8; pk0 = ((unsigned)d4.x << 16) | (unsigned)s4.x;
            bk1 = d4.y >> 8; pk1 = ((unsigned)d4.y << 16) | (unsigned)s4.y;
            bk2 = d4.z >> 8; pk2 = ((unsigned)d4.z << 16) | (unsigned)s4.z;
            bk3 = d4.w >> 8; pk3 = ((unsigned)d4.w << 16) | (unsigned)s4.w;
            rk0 = atomicAdd(&h[bk0], 1);
            rk1 = atomicAdd(&h[bk1], 1);
            rk2 = atomicAdd(&h[bk2], 1);
            rk3 = atomicAdd(&h[bk3], 1);
        }
        __syncthreads();
        if (t < NBUCK) {
            int c = h[t];
            base[t] = c ? (t * CAP + atomicAdd(&cur_pad[t * PAD], c)) : 0;
        }
        __syncthreads();
        if (ok) {
            ebuf[base[bk0] + rk0] = pk0;
            ebuf[base[bk1] + rk1] = pk1;
            ebuf[base[bk2] + rk2] = pk2;
            ebuf[base[bk3] + rk3] = pk3;
        }
    }
}

// ---------------------------------------------------------------------------
// bucket CSR finalize: one block per bucket (256 nodes), 512 THREADS (8
// waves): halves the per-block critical path of the two LDS-atomic passes
// (rounds 18 -> 9) -- important because 196 blocks on 256 CUs leaves no TLP
// to hide per-block latency. Threads 256..511 carry zero through the bin
// scan (bins are owned by t<256). Pad-fill each node's segment tail
// [deg, ceil8(deg)) with ZROW; coalesced uint4 writeback.
// ---------------------------------------------------------------------------
__global__ __launch_bounds__(512)
void bucket_csr_kernel(const unsigned* __restrict__ ebuf, const int* __restrict__ cur_pad,
                       int* __restrict__ row_start, unsigned short* __restrict__ degs,
                       unsigned short* __restrict__ csr) {
    __shared__ int cnt[256];
    __shared__ int cur[256];
    __shared__ int wtot[8], wincl[8];
    __shared__ __align__(16) unsigned short sC[CAP2];
    const int b = blockIdx.x;
    const int t = threadIdx.x;            // 0..511
    const int lane = t & 63, w = t >> 6;  // w 0..7
    const int s = b * CAP;                // ebuf window
    const int m = cur_pad[b * PAD];       // edges in this bucket (<= CAP)
    const int s2 = b * CAP2;              // csr window (8-aligned rows)

    if (t < 256) cnt[t] = 0;
    __syncthreads();

    // one global pass: load to registers + LDS histogram (9 rounds of 512)
    unsigned pk[9];
#pragma unroll
    for (int k = 0; k < 9; ++k) {
        int i = k * 512 + t;
        if (i < m) {
            pk[k] = ebuf[s + i];
            atomicAdd(&cnt[(pk[k] >> 16) & 255], 1);
        }
    }
    __syncthreads();

    const int c  = (t < 256) ? cnt[t] : 0;
    const int c8 = (c + 7) & ~7;          // 8-aligned segment size
    // exclusive scan of c8 across the first 256 threads (waves 4..7 carry 0)
    int sv = c8;
#pragma unroll
    for (int off = 1; off < 64; off <<= 1) {
        int u = __shfl_up(sv, off, 64);
        if (lane >= off) sv += u;
    }
    if (lane == 63) wtot[w] = sv;
    __syncthreads();
    if (w == 0 && lane < 8) {
        int incl = 0;
#pragma unroll
        for (int k = 0; k < 8; ++k)
            if (k <= lane) incl += wtot[k];
        wincl[lane] = incl;
    }
    __syncthreads();
    const int ex = (w ? wincl[w - 1] : 0) + sv - c8;

    int node = b * 256 + t;
    if (t < 256) {
        cur[t] = ex;                      // LOCAL (bucket-relative) cursor
        if (node < N_NODES) {
            row_start[node] = s2 + ex;
            degs[node] = (unsigned short)c;
        }
    }
    __syncthreads();

    // scatter into LDS csr image (9 rounds of 512)
#pragma unroll
    for (int k = 0; k < 9; ++k) {
        int i = k * 512 + t;
        if (i < m) {
            int pos = atomicAdd(&cur[(pk[k] >> 16) & 255], 1);
            sC[pos] = (unsigned short)pk[k];
        }
    }
    __syncthreads();

    // pad each node's segment tail with ZROW (zero-row gather target)
    if (t < 256)
        for (int i = c; i < c8; ++i)
            sC[ex + i] = (unsigned short)ZROW;
    __syncthreads();

    // coalesced writeback of the used prefix (tot is a multiple of 8)
    const int tot = wincl[3];             // waves 4..7 contributed 0
    for (int i = t * 8; i < tot; i += 4096)
        *(uint4*)(csr + s2 + i) = *(const uint4*)(&sC[i]);
}

// ---------------------------------------------------------------------------
// fused SAGE layer, slot-parallel gather with batched index loads.
// Block = 128 (2 waves), 16 nodes. Wave = 8 slots x 8 lanes; slot owns node
// r = w*8+slot; lane covers col-oct c. Indices come 8-at-a-time via one
// 16B-aligned uint4 load; 8 row loads in flight per slot; next index batch
// prefetched across the back-edge. Segments are padded to a multiple of 8
// with ZROW (zero row) -> NO tail code; mean divides by true deg+1.
// Sums held as f32x2 pairs -> v_pk_add_f32 (per-component IEEE adds in the
// same order => bit-identical to scalar version, ~25% fewer ACC VALU ops).
// mean+self staged in LDS bf16, octs XOR-swizzled by row&7. MFMA: wave w does
// col-tiles 2w,2w+1.
// A[m=lane&15][k=(lane>>4)*8+j]; C/D: col=lane&15, row=(lane>>4)*4+reg.
// Grid 3125 (x16 = 50000 exactly).
// ---------------------------------------------------------------------------
template <bool OUT_BF16>
__global__ __launch_bounds__(128)
void sage_fused_kernel(const unsigned short* __restrict__ xb,
                       const int* __restrict__ row_start,
                       const unsigned short* __restrict__ degs,
                       const unsigned short* __restrict__ csr,
                       const unsigned short* __restrict__ pWl,
                       const float* __restrict__ bl,
                       const unsigned short* __restrict__ pWr,
                       float* __restrict__ out_f32,
                       unsigned short* __restrict__ out_bf) {
    __shared__ __align__(16) unsigned short smean[16][FDIM];
    __shared__ __align__(16) unsigned short sxs[16][FDIM];

    const int w = threadIdx.x >> 6;       // 0..1
    const int lane = threadIdx.x & 63;
    const int slot = lane >> 3;           // 0..7 -> node within wave
    const int c = lane & 7;               // col-oct 0..7
    const int base = blockIdx.x * 16;
    const int r = w * 8 + slot;           // local row 0..15
    const int n = base + r;

    // self row first (issues earliest)
    uint4 sv = *(const uint4*)(xb + (size_t)n * FDIM + c * 8);

    const int rs = row_start[n];
    const int deg = degs[n];
    const int po = (c ^ (r & 7)) * 8;     // swizzled physical oct offset

    *(uint4*)(&sxs[r][po]) = sv;
    f32x2 p0 = {bf2f_lo(sv.x), bf2f_hi(sv.x)};
    f32x2 p1 = {bf2f_lo(sv.y), bf2f_hi(sv.y)};
    f32x2 p2 = {bf2f_lo(sv.z), bf2f_hi(sv.z)};
    f32x2 p3 = {bf2f_lo(sv.w), bf2f_hi(sv.w)};

#define ACC(v_) do {                                         \
        p0 += (f32x2){bf2f_lo(v_.x), bf2f_hi(v_.x)};         \
        p1 += (f32x2){bf2f_lo(v_.y), bf2f_hi(v_.y)};         \
        p2 += (f32x2){bf2f_lo(v_.z), bf2f_hi(v_.z)};         \
        p3 += (f32x2){bf2f_lo(v_.w), bf2f_hi(v_.w)};         \
    } while (0)

    const int nb = (deg + 7) >> 3;        // segments padded to x8 with ZROW
    int idx = rs;                         // 8-aligned by construction
    uint4 iA = *(const uint4*)(csr + idx);   // first index batch (unused if nb==0)
    for (int it = 0; it < nb; ++it) {
        int a0 = iA.x & 0xffff, a1 = iA.x >> 16;
        int a2 = iA.y & 0xffff, a3 = iA.y >> 16;
        int a4 = iA.z & 0xffff, a5 = iA.z >> 16;
        int a6 = iA.w & 0xffff, a7 = iA.w >> 16;
        uint4 v0 = *(const uint4*)(xb + (size_t)a0 * FDIM + c * 8);
        uint4 v1 = *(const uint4*)(xb + (size_t)a1 * FDIM + c * 8);
        uint4 v2 = *(const uint4*)(xb + (size_t)a2 * FDIM + c * 8);
        uint4 v3 = *(const uint4*)(xb + (size_t)a3 * FDIM + c * 8);
        uint4 v4 = *(const uint4*)(xb + (size_t)a4 * FDIM + c * 8);
        uint4 v5 = *(const uint4*)(xb + (size_t)a5 * FDIM + c * 8);
        uint4 v6 = *(const uint4*)(xb + (size_t)a6 * FDIM + c * 8);
        uint4 v7 = *(const uint4*)(xb + (size_t)a7 * FDIM + c * 8);
        if (it + 1 < nb)                  // prefetch next index batch across back-edge
            iA = *(const uint4*)(csr + idx + 8);
        ACC(v0); ACC(v1); ACC(v2); ACC(v3);
        ACC(v4); ACC(v5); ACC(v6); ACC(v7);
        idx += 8;
    }
#undef ACC

    const float inv = 1.0f / (float)(deg + 1);
    const f32x2 iv = {inv, inv};
    p0 *= iv; p1 *= iv; p2 *= iv; p3 *= iv;
    uint4 o;
    o.x = f2bf(p0.x) | (f2bf(p0.y) << 16);
    o.y = f2bf(p1.x) | (f2bf(p1.y) << 16);
    o.z = f2bf(p2.x) | (f2bf(p2.y) << 16);
    o.w = f2bf(p3.x) | (f2bf(p3.y) << 16);
    *(uint4*)(&smean[r][po]) = o;
    __syncthreads();

    // ---- MFMA phase: wave w -> col-tiles 2w, 2w+1 ----
    const int qq = lane >> 4;
    const int rr = lane & 15;

    short8 am0 = *(const short8*)(&smean[rr][((0 + qq) ^ (rr & 7)) * 8]);
    short8 am1 = *(const short8*)(&smean[rr][((4 + qq) ^ (rr & 7)) * 8]);
    short8 ax0 = *(const short8*)(&sxs[rr][((0 + qq) ^ (rr & 7)) * 8]);
    short8 ax1 = *(const short8*)(&sxs[rr][((4 + qq) ^ (rr & 7)) * 8]);

    const short8* pl = (const short8*)pWl;
    const short8* pr = (const short8*)pWr;

#pragma unroll
    for (int tk = 0; tk < 2; ++tk) {
        const int ct = w * 2 + tk;
        short8 bl0v = pl[(ct * 2 + 0) * 64 + lane];
        short8 bl1v = pl[(ct * 2 + 1) * 64 + lane];
        short8 br0v = pr[(ct * 2 + 0) * 64 + lane];
        short8 br1v = pr[(ct * 2 + 1) * 64 + lane];

        float b = bl[ct * 16 + rr];
        f32x4 acc = {b, b, b, b};
        acc = __builtin_amdgcn_mfma_f32_16x16x32_bf16(am0, bl0v, acc, 0, 0, 0);
        acc = __builtin_amdgcn_mfma_f32_16x16x32_bf16(am1, bl1v, acc, 0, 0, 0);
        acc = __builtin_amdgcn_mfma_f32_16x16x32_bf16(ax0, br0v, acc, 0, 0, 0);
        acc = __builtin_amdgcn_mfma_f32_16x16x32_bf16(ax1, br1v, acc, 0, 0, 0);

#pragma unroll
        for (int reg = 0; reg < 4; ++reg) {
            int node = base + qq * 4 + reg;
            float v = fmaxf(acc[reg], 0.0f);
            if (OUT_BF16) out_bf[(size_t)node * FDIM + ct * 16 + rr] = (unsigned short)f2bf(v);
            else          out_f32[(size_t)node * FDIM + ct * 16 + rr] = v;
        }
    }
}

// ---------------------------------------------------------------------------
extern "C" void kernel_launch(void* const* d_in, const int* in_sizes, int n_in,
                              void* d_out, int out_size, void* d_ws, size_t ws_size,
                              hipStream_t stream) {
    const float* x0  = (const float*)d_in[0];
    const int*   ei  = (const int*)d_in[1];
    const float* Wl0 = (const float*)d_in[2];
    const float* bl0 = (const float*)d_in[3];
    const float* Wr0 = (const float*)d_in[4];
    const float* Wl1 = (const float*)d_in[5];
    const float* bl1 = (const float*)d_in[6];
    const float* Wr1 = (const float*)d_in[7];
    float* out = (float*)d_out;

    const int* src = ei;            // edge_index[0]
    const int* dst = ei + N_EDGES;  // edge_index[1]

    // workspace layout (all segments 16B-aligned by construction):
    // cur_pad[3136] | row_start[50000] | degs u16[50000] | ebuf[196*4608] |
    // csr u16[196*5632 + 1024 slack] | x_bf[(N+1)*64] | h_bf[(N+1)*64] | pW(4x4096)
    int* cur_pad    = (int*)d_ws;                        // 3136 ints
    int* row_start  = cur_pad + 3136;                    // 50000 ints
    unsigned short* degs = (unsigned short*)(row_start + 50000);   // 50000
    unsigned* ebuf  = (unsigned*)(degs + 50000);         // 903168 uints
    unsigned short* csr_u16 = (unsigned short*)(ebuf + NBUCK * CAP);
    unsigned short* x_bf = csr_u16 + (NBUCK * CAP2 + 1024);
    unsigned short* h_bf = x_bf + (size_t)(N_NODES + 1) * FDIM;
    unsigned short* pW   = h_bf + (size_t)(N_NODES + 1) * FDIM;   // 4 x 4096

    hipMemsetAsync(cur_pad, 0, 3136 * sizeof(int), stream);
    preprocess_kernel<<<3912, 256, 0, stream>>>(x0, x_bf, h_bf, Wl0, Wr0, Wl1, Wr1,
                                                pW, src, dst, cur_pad, ebuf);
    bucket_csr_kernel<<<NBUCK, 512, 0, stream>>>(ebuf, cur_pad, row_start, degs, csr_u16);

    // ---- layer 0 (bf16 out) ----
    sage_fused_kernel<true><<<N_NODES / 16, 128, 0, stream>>>(
        x_bf, row_start, degs, csr_u16, pW + 0 * FDIM * FDIM, bl0,
        pW + 1 * FDIM * FDIM, nullptr, h_bf);
    // ---- layer 1 (fp32 out) ----
    sage_fused_kernel<false><<<N_NODES / 16, 128, 0, stream>>>(
        h_bf, row_start, degs, csr_u16, pW + 2 * FDIM * FDIM, bl1,
        pW + 3 * FDIM * FDIM, out, nullptr);
}